// Round 12
// baseline (52.950 us; speedup 1.0000x reference)
//
#include <hip/hip_runtime.h>

// NCuts loss: seg [8,4,224,224], padded_seg [8,4,232,232],
// weight [8,1,224,224,9,9], sum_weight [8,1,224,224] -> out[8] (fp32)
//
// stage1: persistent blocks, grid = 256 = #CUs (LDS 92KB -> 1 block/CU),
// block owns 7 consecutive rows (28 tiles of 56 px).
//  - psg window: 15 padded rows in CLASS-PAIR layout [slot][pair][232]{c0,c1}
//    (float2) staged once in the prologue (register path, packed f4 writes).
//    One ds_read_b64 per tap per pair -> tap = 1 b32 + 2 b64 (was 5 b32):
//    cuts the dominant LDS-instruction cost ~40%.
//  - weight: 28 tiles double-buffered via global_load_lds; per-wave
//    CONTIGUOUS 142-f4 chunks -> exactly 3 GLL16/wave/tile, NO padding
//    (round-11's +35% padded DMA was the regression). Counted vmcnt(3)
//    keeps the prefetch in flight across raw s_barriers; vmcnt(0) only on
//    the last tile.
//  - seg read from the psg window interior; sum_weight recomputed as the
//    tap-sum of staged weights -> no global loads in the loop besides DMA.
//  - 81 taps over 8 waves, compile-time tap offsets, register rA/rV fold,
//    single block-end reduction.

constexpr int NN  = 8;
constexpr int KK  = 4;
constexpr int HH  = 224;
constexpr int WW  = 224;
constexpr int PAD = 4;                   // RADIUS-1
constexpr int HP  = HH + 2 * PAD;        // 232
constexpr int WP  = WW + 2 * PAD;        // 232
constexpr int NWIN = 81;
constexpr int PIX = HH * WW;             // 50176
constexpr int TPB = 512;                 // 8 waves
constexpr int PPB = 56;                  // pixels per tile
constexpr int TPR = WW / PPB;            // 4 tiles per row
constexpr int RPB = 7;                   // rows per block
constexpr int GPI = HH / RPB;            // 32 row-groups per image
constexpr int NBLK = NN * GPI;           // 256 blocks == #CUs
constexpr int PLANE = HP * WP;           // 53824
constexpr int NSLOT = RPB + 8;           // 15 padded rows resident
constexpr int ROWF2 = 2 * WP;            // 464 float2 per slot (2 pairs x 232)
constexpr int PSGALL4 = NSLOT * ROWF2 / 2;  // 3480 f4 total
constexpr int WSLAB = PPB * NWIN;        // 4536 floats per weight tile
constexpr int WF4 = WSLAB / 4;           // 1134 f4 per tile
constexpr int CW  = 142;                 // f4 chunk per wave (wave7: 140)
constexpr int NTILE = RPB * TPR;         // 28 weight tiles per block

#define GLL16(gptr, lptr)                                            \
    __builtin_amdgcn_global_load_lds(                                \
        (const __attribute__((address_space(1))) void*)(gptr),       \
        (__attribute__((address_space(3))) void*)(lptr), 16, 0, 0)

template<int T0, int T1>
__device__ inline void do_taps(const float* __restrict__ lwp,
                               const float2* __restrict__ pbase,
                               float acc[KK], float& wsum) {
#pragma unroll
    for (int t = T0; t < T1; ++t) {
        const int m = t / 9;
        const int j = t - 9 * m;               // compile-time after unroll
        const float wv = lwp[t];               // ds_read_b32 (pairable -> read2)
        wsum += wv;
        const float2 p01 = pbase[(m * 2 + 0) * WP + j];   // ds_read_b64
        const float2 p23 = pbase[(m * 2 + 1) * WP + j];   // ds_read_b64
        acc[0] += p01.x * wv;
        acc[1] += p01.y * wv;
        acc[2] += p23.x * wv;
        acc[3] += p23.y * wv;
    }
}

__global__ __launch_bounds__(TPB) void ncuts_stage1(
    const float* __restrict__ seg, const float* __restrict__ pseg,
    const float* __restrict__ wgt, const float* __restrict__ swgt,
    float* __restrict__ part)
{
    const int b    = blockIdx.x;             // n*32 + row-group
    const int n    = b >> 5;
    const int h0   = (b & 31) * RPB;         // first image row of this block
    const int tid  = threadIdx.x;
    const int wv_  = tid >> 6;               // 0..7
    const int lane = tid & 63;

    __shared__ float lds_w[2 * WSLAB];          // 36288 B (double buffer)
    __shared__ float2 psg_lds[NSLOT * ROWF2];   // 55680 B [slot][pair][232]{2}
    __shared__ float lred[8][8];                // 256 B -> 92224 B total

    const size_t nb = (size_t)n * KK * PLANE;
    const float* wbase = wgt + ((size_t)n * PIX + (size_t)h0 * WW) * NWIN;

    // ---- weight stager: per-wave contiguous chunk, EXACTLY 3 GLL16/wave ----
    const int cbase = wv_ * CW;                       // chunk start (f4)
    const int clen  = (wv_ == 7) ? (WF4 - 7 * CW) : CW;   // 140 or 142
    auto stage_w = [&](int buf, int ti) {
        const float4* wsrc = (const float4*)(wbase + (size_t)ti * WSLAB);
        float* base = lds_w + buf * WSLAB;
#pragma unroll
        for (int k = 0; k < 3; ++k) {
            const int o = k * 64 + lane;              // offset within chunk
            if (o < clen)                             // every wave: >=1 lane on
                GLL16(wsrc + cbase + o, base + ((cbase + k * 64) << 2));
        }
    };

    stage_w(0, 0);                            // async: weight tile 0

    // ---- prologue: psg 15 rows, pair-packed, register staging ----
    for (int i = tid; i < PSGALL4; i += TPB) {
        const int slot = i / 232;                     // 232 f4 per slot
        const int r    = i - slot * 232;
        const int pr   = r / 116;                     // class pair 0/1
        const int col2 = (r - pr * 116) * 2;          // even col
        const float* g0 = pseg + nb + (size_t)(2 * pr)     * PLANE +
                          (size_t)(h0 + slot) * WP + col2;
        const float* g1 = pseg + nb + (size_t)(2 * pr + 1) * PLANE +
                          (size_t)(h0 + slot) * WP + col2;
        const float2 a = *(const float2*)g0;          // c_even cols col2,col2+1
        const float2 c = *(const float2*)g1;          // c_odd
        float4 v;  v.x = a.x; v.y = c.x; v.z = a.y; v.w = c.y;
        *(float4*)((float*)psg_lds + (size_t)i * 4) = v;
    }

    float rA[KK] = {0.f, 0.f, 0.f, 0.f};
    float rV[KK] = {0.f, 0.f, 0.f, 0.f};

    __syncthreads();   // prologue-only full drain: psg + weight tile 0 landed

    int cur = 0;
#pragma unroll 1
    for (int ti = 0; ti < NTILE; ++ti) {
        const int s  = ti >> 2;              // row-step 0..6
        const int tt = ti & 3;               // tile in row

        // ---- issue next tile's DMA (3/wave), counted wait on current ----
        if (ti + 1 < NTILE) {
            stage_w(cur ^ 1, ti + 1);
            asm volatile("s_waitcnt vmcnt(3)" ::: "memory");  // tile ti landed
        } else {
            asm volatile("s_waitcnt vmcnt(0)" ::: "memory");  // last tile
        }
        __builtin_amdgcn_s_barrier();        // everyone's tile ti visible

        // ---- compute tile ti from LDS; fold into rA/rV ----
        if (lane < PPB) {
            const int colp = tt * PPB + lane;         // padded col (pixel-4)
            const float2* pbase = psg_lds + (size_t)s * ROWF2 + colp;
            float segv[KK];
            {   // seg = psg interior: slot s+4, col colp+4
                const float2 s01 = pbase[(8 + 0) * WP + 4];
                const float2 s23 = pbase[(8 + 1) * WP + 4];
                segv[0] = s01.x; segv[1] = s01.y;
                segv[2] = s23.x; segv[3] = s23.y;
            }
            const float* lwp = lds_w + cur * WSLAB + lane * NWIN;
            float acc[KK] = {0.f, 0.f, 0.f, 0.f};
            float wsum = 0.f;
            switch (wv_) {
                case 0:  do_taps<0, 10>(lwp, pbase, acc, wsum); break;
                case 1:  do_taps<10, 20>(lwp, pbase, acc, wsum); break;
                case 2:  do_taps<20, 30>(lwp, pbase, acc, wsum); break;
                case 3:  do_taps<30, 40>(lwp, pbase, acc, wsum); break;
                case 4:  do_taps<40, 50>(lwp, pbase, acc, wsum); break;
                case 5:  do_taps<50, 60>(lwp, pbase, acc, wsum); break;
                case 6:  do_taps<60, 70>(lwp, pbase, acc, wsum); break;
                default: do_taps<70, 81>(lwp, pbase, acc, wsum); break;
            }
#pragma unroll
            for (int c = 0; c < KK; ++c) {
                rA[c] += acc[c] * segv[c];
                rV[c] += wsum   * segv[c];
            }
        }
        __builtin_amdgcn_s_barrier();        // all reads of buf cur consumed
        cur ^= 1;                            //  (lgkmcnt forced by FMA deps)
    }

    // ---- single block-end reduction ----
    float vals[8] = { rA[0], rA[1], rA[2], rA[3], rV[0], rV[1], rV[2], rV[3] };
#pragma unroll
    for (int i = 0; i < 8; ++i) {
        float v = vals[i];
#pragma unroll
        for (int off = 32; off > 0; off >>= 1) v += __shfl_down(v, off, 64);
        if (lane == 0) lred[wv_][i] = v;
    }
    __syncthreads();
    if (tid < 8) {
        float ssum = 0.f;
#pragma unroll
        for (int w = 0; w < 8; ++w) ssum += lred[w][tid];
        part[(size_t)b * 8 + tid] = ssum;
    }
}

__global__ __launch_bounds__(256) void ncuts_stage2(
    const float* __restrict__ part, float* __restrict__ out)
{
    const int n   = blockIdx.x;
    const int tid = threadIdx.x;

    float vals[8] = {0.f, 0.f, 0.f, 0.f, 0.f, 0.f, 0.f, 0.f};
    for (int bb = tid; bb < GPI; bb += 256) {       // 32 entries per image
        const float* q = part + ((size_t)(n * GPI + bb)) * 8;
#pragma unroll
        for (int i = 0; i < 8; ++i) vals[i] += q[i];
    }

    __shared__ float lred[4][8];
    const int lane = tid & 63;
    const int wv_  = tid >> 6;
#pragma unroll
    for (int i = 0; i < 8; ++i) {
        float v = vals[i];
#pragma unroll
        for (int off = 32; off > 0; off >>= 1) v += __shfl_down(v, off, 64);
        if (lane == 0) lred[wv_][i] = v;
    }
    __syncthreads();
    if (tid == 0) {
        float assoc = 0.f;
#pragma unroll
        for (int k = 0; k < 4; ++k) {
            const float A = lred[0][k] + lred[1][k] + lred[2][k] + lred[3][k];
            const float V = lred[0][4 + k] + lred[1][4 + k] + lred[2][4 + k] + lred[3][4 + k];
            assoc += A / V;
        }
        out[n] = 4.0f - assoc;
    }
}

extern "C" void kernel_launch(void* const* d_in, const int* in_sizes, int n_in,
                              void* d_out, int out_size, void* d_ws, size_t ws_size,
                              hipStream_t stream) {
    const float* seg  = (const float*)d_in[0];
    const float* pseg = (const float*)d_in[1];
    const float* wgt  = (const float*)d_in[2];
    const float* swgt = (const float*)d_in[3];
    float* out  = (float*)d_out;
    float* part = (float*)d_ws;   // 256 blocks * 8 floats = 8192 B

    ncuts_stage1<<<NBLK, TPB, 0, stream>>>(seg, pseg, wgt, swgt, part);
    ncuts_stage2<<<NN, 256, 0, stream>>>(part, out);
}

// Round 13
// 36.593 us; speedup vs baseline: 1.4470x; 1.4470x over previous
//
#include <hip/hip_runtime.h>

// NCuts loss: seg [8,4,224,224], padded_seg [8,4,232,232],
// weight [8,1,224,224,9,9], sum_weight [8,1,224,224] -> out[8] (fp32)
//
// stage1: 1024 blocks = 8 img x 32 row-groups x 4 col-strips; each block =
// 7 rows x 56 cols. LDS 51.9KB -> 3 blocks/CU (24 waves) so __syncthreads
// drains overlap across blocks (R10 was 1 block/CU: every drain idled the
// whole CU). R10-proven sync structure (stage-next, compute, syncthreads);
// counted-vmcnt/b64 variants of R11/R12 regressed and are reverted.
//  - psg window: 15 x 4cls x 64cols (15.4 KB) staged once via global_load_lds.
//    seg read from window interior; sum_weight recomputed from staged
//    weights -> no global loads in the loop besides the weight DMA.
//  - weight: 7 row-tiles (56px*81 = 18.1KB, 16B-aligned), double-buffered
//    global_load_lds, prefetch 1 tile ahead.
//  - 81 taps over 8 waves, compile-time offsets, b32 reads (proven
//    conflict-free), register rA/rV fold, single block-end reduction.
//  - bijective XCD swizzle (1024 % 8 == 0) for psg L2 locality.

constexpr int NN  = 8;
constexpr int KK  = 4;
constexpr int HH  = 224;
constexpr int WW  = 224;
constexpr int PAD = 4;                   // RADIUS-1
constexpr int HP  = HH + 2 * PAD;        // 232
constexpr int WP  = WW + 2 * PAD;        // 232
constexpr int NWIN = 81;
constexpr int PIX = HH * WW;             // 50176
constexpr int TPB = 512;                 // 8 waves
constexpr int PPB = 56;                  // tile/strip width
constexpr int RPB = 7;                   // rows per block
constexpr int CSP = WW / PPB;            // 4 col-strips
constexpr int GPI = HH / RPB;            // 32 row-groups
constexpr int BPI = GPI * CSP;           // 128 blocks per image
constexpr int NBLK = NN * BPI;           // 1024 blocks
constexpr int PLANE = HP * WP;           // 53824
constexpr int WCOL = PPB + 8;            // 64 window cols
constexpr int NSLOT = RPB + 8;           // 15 window rows
constexpr int PSG_F4 = NSLOT * KK * (WCOL / 4);  // 960 f4 = 15.4 KB
constexpr int WSLAB = PPB * NWIN;        // 4536 floats per weight tile
constexpr int WF4 = WSLAB / 4;           // 1134 f4

#define GLL16(gptr, lptr)                                            \
    __builtin_amdgcn_global_load_lds(                                \
        (const __attribute__((address_space(1))) void*)(gptr),       \
        (__attribute__((address_space(3))) void*)(lptr), 16, 0, 0)

template<int T0, int T1>
__device__ inline void do_taps(const float* __restrict__ lwp,
                               const float* __restrict__ psl,
                               float acc[KK], float& wsum) {
#pragma unroll
    for (int t = T0; t < T1; ++t) {
        const int m = t / 9;
        const int j = t - 9 * m;          // compile-time after unroll
        const float wv = lwp[t];          // ds_read_b32, immediate offset
        wsum += wv;
#pragma unroll
        for (int c = 0; c < KK; ++c)      // [slot][cls][64]: offsets compile-time
            acc[c] += psl[(m * KK + c) * WCOL + j] * wv;
    }
}

__global__ __launch_bounds__(TPB, 6) void ncuts_stage1(
    const float* __restrict__ seg, const float* __restrict__ pseg,
    const float* __restrict__ wgt, const float* __restrict__ swgt,
    float* __restrict__ part)
{
    const int hw   = blockIdx.x;
    const int b    = (hw & 7) * (NBLK / 8) + (hw >> 3);  // XCD-contiguous swizzle
    const int n    = b / BPI;
    const int r    = b - n * BPI;
    const int rg   = r >> 2;                 // row-group 0..31
    const int cs   = r & 3;                  // col-strip 0..3
    const int h0   = rg * RPB;
    const int w0   = cs * PPB;
    const int tid  = threadIdx.x;
    const int wv_  = tid >> 6;               // 0..7
    const int lane = tid & 63;

    __shared__ float lds_w[2 * WSLAB];                 // 36288 B
    __shared__ float psg_lds[NSLOT * KK * WCOL];       // 15360 B
    __shared__ float lred[8][8];                       // 256 B -> 51904 B

    const size_t nb = (size_t)n * KK * PLANE;

    // ---- weight tile stager (R10-proven): 16B-aligned tile base ----
    auto stage_w = [&](int buf, int s) {
        const float4* wsrc = (const float4*)(
            wgt + ((size_t)n * PIX + (size_t)(h0 + s) * WW + w0) * NWIN);
        float* base = lds_w + buf * WSLAB;
#pragma unroll
        for (int k = 0; k < 3; ++k) {
            const int i = k * TPB + tid;
            if (i < WF4)
                GLL16(wsrc + i, base + ((k * TPB + (tid & ~63)) << 2));
        }
    };

    stage_w(0, 0);                            // async: weight tile 0

    // ---- psg window prologue: [15 slots][4 cls][64 cols], 960 f4 ----
#pragma unroll
    for (int k = 0; k < 2; ++k) {
        const int i = k * TPB + tid;
        if (i < PSG_F4) {
            const int slot = i >> 6;              // /64 (16 f4 * 4 cls)
            const int c    = (i >> 4) & 3;
            const int c4   = i & 15;
            const float* src = pseg + nb + (size_t)c * PLANE +
                               (size_t)(h0 + slot) * WP + w0 + c4 * 4;
            GLL16(src, psg_lds + ((k * TPB + (tid & ~63)) << 2));
        }
    }

    float rA[KK] = {0.f, 0.f, 0.f, 0.f};
    float rV[KK] = {0.f, 0.f, 0.f, 0.f};

    __syncthreads();   // psg window + weight tile 0 landed

    int cur = 0;
#pragma unroll 1
    for (int s = 0; s < RPB; ++s) {
        // ---- prefetch next row-tile's weights into the other buffer ----
        if (s + 1 < RPB) stage_w(cur ^ 1, s + 1);

        // ---- compute row s from LDS; fold into rA/rV ----
        if (lane < PPB) {
            const float* psl = psg_lds + (size_t)s * KK * WCOL + lane;
            float segv[KK];
#pragma unroll
            for (int c = 0; c < KK; ++c)          // seg = window interior
                segv[c] = psl[((4 * KK) + c) * WCOL + 4];
            const float* lwp = lds_w + cur * WSLAB + lane * NWIN;
            float acc[KK] = {0.f, 0.f, 0.f, 0.f};
            float wsum = 0.f;
            switch (wv_) {
                case 0:  do_taps<0, 10>(lwp, psl, acc, wsum); break;
                case 1:  do_taps<10, 20>(lwp, psl, acc, wsum); break;
                case 2:  do_taps<20, 30>(lwp, psl, acc, wsum); break;
                case 3:  do_taps<30, 40>(lwp, psl, acc, wsum); break;
                case 4:  do_taps<40, 50>(lwp, psl, acc, wsum); break;
                case 5:  do_taps<50, 60>(lwp, psl, acc, wsum); break;
                case 6:  do_taps<60, 70>(lwp, psl, acc, wsum); break;
                default: do_taps<70, 81>(lwp, psl, acc, wsum); break;
            }
#pragma unroll
            for (int c = 0; c < KK; ++c) {
                rA[c] += acc[c] * segv[c];
                rV[c] += wsum   * segv[c];
            }
        }
        __syncthreads();   // tile consumed; prefetch drained (overlapped by
        cur ^= 1;          //   the other 2 resident blocks on this CU)
    }

    // ---- single block-end reduction ----
    float vals[8] = { rA[0], rA[1], rA[2], rA[3], rV[0], rV[1], rV[2], rV[3] };
#pragma unroll
    for (int i = 0; i < 8; ++i) {
        float v = vals[i];
#pragma unroll
        for (int off = 32; off > 0; off >>= 1) v += __shfl_down(v, off, 64);
        if (lane == 0) lred[wv_][i] = v;
    }
    __syncthreads();
    if (tid < 8) {
        float ssum = 0.f;
#pragma unroll
        for (int w = 0; w < 8; ++w) ssum += lred[w][tid];
        part[(size_t)b * 8 + tid] = ssum;
    }
}

__global__ __launch_bounds__(256) void ncuts_stage2(
    const float* __restrict__ part, float* __restrict__ out)
{
    const int n   = blockIdx.x;
    const int tid = threadIdx.x;

    float vals[8] = {0.f, 0.f, 0.f, 0.f, 0.f, 0.f, 0.f, 0.f};
    for (int bb = tid; bb < BPI; bb += 256) {       // 128 entries per image
        const float* q = part + ((size_t)(n * BPI + bb)) * 8;
#pragma unroll
        for (int i = 0; i < 8; ++i) vals[i] += q[i];
    }

    __shared__ float lred[4][8];
    const int lane = tid & 63;
    const int wv_  = tid >> 6;
#pragma unroll
    for (int i = 0; i < 8; ++i) {
        float v = vals[i];
#pragma unroll
        for (int off = 32; off > 0; off >>= 1) v += __shfl_down(v, off, 64);
        if (lane == 0) lred[wv_][i] = v;
    }
    __syncthreads();
    if (tid == 0) {
        float assoc = 0.f;
#pragma unroll
        for (int k = 0; k < 4; ++k) {
            const float A = lred[0][k] + lred[1][k] + lred[2][k] + lred[3][k];
            const float V = lred[0][4 + k] + lred[1][4 + k] + lred[2][4 + k] + lred[3][4 + k];
            assoc += A / V;
        }
        out[n] = 4.0f - assoc;
    }
}

extern "C" void kernel_launch(void* const* d_in, const int* in_sizes, int n_in,
                              void* d_out, int out_size, void* d_ws, size_t ws_size,
                              hipStream_t stream) {
    const float* seg  = (const float*)d_in[0];
    const float* pseg = (const float*)d_in[1];
    const float* wgt  = (const float*)d_in[2];
    const float* swgt = (const float*)d_in[3];
    float* out  = (float*)d_out;
    float* part = (float*)d_ws;   // 1024 blocks * 8 floats = 32768 B

    ncuts_stage1<<<NBLK, TPB, 0, stream>>>(seg, pseg, wgt, swgt, part);
    ncuts_stage2<<<NN, 256, 0, stream>>>(part, out);
}